// Round 6
// baseline (421.461 us; speedup 1.0000x reference)
//
#include <hip/hip_runtime.h>
#include <math.h>

#define Bn 512
#define Sn 1024
#define Tn 48

typedef _Float16 half2v __attribute__((ext_vector_type(2)));

static constexpr float LOG2E = 1.4426950408889634f;
static constexpr float LN2f  = 0.6931471805599453f;
static constexpr float C6    = 0.015625f;   // 2^-6 per-step pre-scale (tracked by 6*cnt)

#if defined(__has_builtin)
#  if __has_builtin(__builtin_amdgcn_fdot2)
#    define HAVE_FDOT2 1
#  endif
#endif
#ifndef HAVE_FDOT2
#  define HAVE_FDOT2 0
#endif

__device__ __forceinline__ float rlanef(float x, int lane) {
  return __int_as_float(__builtin_amdgcn_readlane(__float_as_int(x), lane));
}
__device__ __forceinline__ int rlanei(int x, int lane) {
  return __builtin_amdgcn_readlane(x, lane);
}

template <int CTRL>
__device__ __forceinline__ float dpp_mv_neginf(float x) {
  return __int_as_float(__builtin_amdgcn_update_dpp(
      (int)0xff800000, __float_as_int(x), CTRL, 0xf, 0xf, false));
}
__device__ __forceinline__ float wave_redmax_lane63(float x) {
  x = fmaxf(x, dpp_mv_neginf<0x121>(x));  // row_ror:1
  x = fmaxf(x, dpp_mv_neginf<0x122>(x));  // row_ror:2
  x = fmaxf(x, dpp_mv_neginf<0x124>(x));  // row_ror:4
  x = fmaxf(x, dpp_mv_neginf<0x128>(x));  // row_ror:8
  x = fmaxf(x, dpp_mv_neginf<0x142>(x));  // row_bcast:15
  x = fmaxf(x, dpp_mv_neginf<0x143>(x));  // row_bcast:31
  return x;
}
__device__ __forceinline__ float wave_max_all(float x) {
  return rlanef(wave_redmax_lane63(x), 63);
}

// Sink-proof global->LDS stage: 64 lanes x 16B = 1024B per call.
__device__ __forceinline__ void stage16(const void* g, void* l, int lane) {
  __builtin_amdgcn_global_load_lds(
      (const __attribute__((address_space(1))) void*)((const char*)g + lane * 16),
      (__attribute__((address_space(3))) void*)((char*)l + lane * 16), 16, 0, 0);
}
// Emission chunk stage: 768B of chunk cc into slot (lanes 48-63 clamped dup).
__device__ __forceinline__ void stage_em(const float* emb, float* s_em, int cc,
                                         int slot, int lane) {
  int off = cc * 768 + lane * 16;
  off = off > (Sn * Tn * 4 - 16) ? (Sn * Tn * 4 - 16) : off;
  __builtin_amdgcn_global_load_lds(
      (const __attribute__((address_space(1))) void*)((const char*)emb + off),
      (__attribute__((address_space(3))) void*)((char*)s_em + slot * 1024 + lane * 16),
      16, 0, 0);
}

// 24 packed f16x2 regs: Ehat row jc = 2^(trans'-mtg), values in (0,1].
#define DECL_P1(k) \
  half2v P_##k; { \
    const float e0_ = __builtin_amdgcn_exp2f(fmaf(trow[2*(k)],   LOG2E, -mtg)); \
    const float e1_ = __builtin_amdgcn_exp2f(fmaf(trow[2*(k)+1], LOG2E, -mtg)); \
    P_##k[0] = (_Float16)e0_; P_##k[1] = (_Float16)e1_; }
#define DECL_P_ALL \
  DECL_P1(0)  DECL_P1(1)  DECL_P1(2)  DECL_P1(3)  DECL_P1(4)  DECL_P1(5) \
  DECL_P1(6)  DECL_P1(7)  DECL_P1(8)  DECL_P1(9)  DECL_P1(10) DECL_P1(11) \
  DECL_P1(12) DECL_P1(13) DECL_P1(14) DECL_P1(15) DECL_P1(16) DECL_P1(17) \
  DECL_P1(18) DECL_P1(19) DECL_P1(20) DECL_P1(21) DECL_P1(22) DECL_P1(23)

#if HAVE_FDOT2
#define DOT1(k, a) { const int pk_ = rlanei(hpk, 2*(k)); \
  a = __builtin_amdgcn_fdot2(P_##k, __builtin_bit_cast(half2v, pk_), a, false); }
#else
#define DOT1(k, a) { const int pk_ = rlanei(hpk, 2*(k)); \
  const half2v hb_ = __builtin_bit_cast(half2v, pk_); \
  a = fmaf((float)P_##k[0], (float)hb_[0], fmaf((float)P_##k[1], (float)hb_[1], a)); }
#endif
#define DOT4(k0,k1,k2,k3) DOT1(k0,a0) DOT1(k1,a1) DOT1(k2,a2) DOT1(k3,a3)
#define DOT_ALL \
  DOT4(0,1,2,3)     DOT4(4,5,6,7)     DOT4(8,9,10,11) \
  DOT4(12,13,14,15) DOT4(16,17,18,19) DOT4(20,21,22,23)

__global__ __launch_bounds__(64, 1)
__attribute__((amdgpu_waves_per_eu(1)))
void crf_fwd(
    const float* __restrict__ emissions,
    const int*   __restrict__ tags,
    const float* __restrict__ mask,
    const float* __restrict__ trans,
    const float* __restrict__ startt,
    const float* __restrict__ endt,
    float* __restrict__ per_batch)
{
  __shared__ float s_trans[2304];   // 9216B, staged once
  __shared__ int   s_tags[1024];    // 4096B, staged once
  __shared__ float s_mask[1024];    // 4096B, staged once
  __shared__ float s_tv[1024];      // trans[tag_s, tag_{s-1}], precomputed once
  __shared__ float s_em[1024];      // 4 slots x 256 words (192 data + 64 pad)

  const int b  = blockIdx.x;
  const int j  = threadIdx.x;
  const int jc = (j < Tn) ? j : (Tn - 1);

  const float* __restrict__ emb = emissions + (size_t)b * Sn * Tn;
  const int*   __restrict__ tgb = tags + (size_t)b * Sn;
  const float* __restrict__ mkb = mask + (size_t)b * Sn;

  // ---- One-time staging: trans(9) + tags(4) + mask(4) + em chunks 0..2 ----
  #pragma unroll
  for (int k = 0; k < 9; ++k) stage16(trans + k * 256, &s_trans[k * 256], j);
  #pragma unroll
  for (int k = 0; k < 4; ++k) stage16(tgb + k * 256, &s_tags[k * 256], j);
  #pragma unroll
  for (int k = 0; k < 4; ++k) stage16(mkb + k * 256, &s_mask[k * 256], j);
  stage_em(emb, s_em, 0, 0, j);
  stage_em(emb, s_em, 1, 1, j);
  stage_em(emb, s_em, 2, 2, j);
  asm volatile("s_waitcnt vmcnt(0)" ::: "memory");

  // ---- Constants: mtg + Ehat row (from LDS: remat impossible) ----
  const float* trow = &s_trans[jc * Tn];
  float mt = trow[0];
  #pragma unroll
  for (int i = 1; i < Tn; ++i) mt = fmaxf(mt, trow[i]);
  const float mtg = wave_max_all(mt) * LOG2E;
  DECL_P_ALL

  // ---- Precompute all transition-gather values into LDS (off the loop) ----
  #pragma unroll 4
  for (int it = 0; it < 16; ++it) {
    const int s = it * 64 + j;
    const int sp = (s == 0) ? 0 : s - 1;
    s_tv[s] = s_trans[s_tags[s] * Tn + s_tags[sp]];
  }

  // ---- Init (step 0): w_j = 2^(score_j - M) ----
  const float em0  = s_em[jc];
  const int   tag0 = s_tags[0];
  const float sc0  = (startt[jc] + em0) * LOG2E;
  const float m00  = wave_max_all(sc0);
  float w = __builtin_amdgcn_exp2f(sc0 - m00);
  float M = m00;
  float numer = rlanef(em0, tag0) + startt[tag0];
  float cnt = 0.0f;
  int   lt  = tag0;
  int   hpk = 0;

  auto repack = [&]() {
    const float wn = __int_as_float(__builtin_amdgcn_update_dpp(
        0, __float_as_int(w), 0x111 /*row_shr:1*/, 0xf, 0xf, true));
    half2v hp; hp[0] = (_Float16)w; hp[1] = (_Float16)wn;
    hpk = __builtin_bit_cast(int, hp);
  };
  auto do_step = [&](float em_raw, float e6, float mk, int tg, float tval) {
    float a0 = 0.f, a1 = 0.f, a2 = 0.f, a3 = 0.f;
    DOT_ALL
    const float nxt = ((a0 + a1) + (a2 + a3)) * e6;
    const bool on = (mk > 0.0f);
    w = on ? nxt : w;
    numer = fmaf(mk, rlanef(em_raw, tg) + tval, numer);
    cnt += mk;
    lt = on ? tg : lt;
  };
  float pendS = 1.0f, pendM = 0.0f, scA = 1.0f, mA = 0.0f;
  auto measure = [&](float& S, float& A) {
    const float mx = wave_redmax_lane63(w);
    const int ms = rlanei(__float_as_int(mx), 63);
    const int mb = ms & 0x7f800000;
    S = __int_as_float(0x7f000000 - mb);   // exact 2^-E (uniform)
    A = (float)((mb >> 23) - 127);
  };

  repack();
  // ---- Prologue: steps 1..3 (chunk 0, already in LDS slot 0) ----
  {
    const float e1r = s_em[48 + jc], e2r = s_em[96 + jc], e3r = s_em[144 + jc];
    const float e61 = __builtin_amdgcn_exp2f(e1r * LOG2E) * C6;
    const float e62 = __builtin_amdgcn_exp2f(e2r * LOG2E) * C6;
    const float e63 = __builtin_amdgcn_exp2f(e3r * LOG2E) * C6;
    do_step(e1r, e61, s_mask[1], s_tags[1], s_tv[1]);
    measure(scA, mA);
    repack();
    do_step(e2r, e62, s_mask[2], s_tags[2], s_tv[2]);
    repack();
    do_step(e3r, e63, s_mask[3], s_tags[3], s_tv[3]);
    w *= scA; M += mA;
    measure(pendS, pendM);
    repack();
  }
  stage_em(emb, s_em, 3, 3, j);

  // ---- Main loop: chunk c = steps 4c..4c+3; 3-deep em pipeline ----
  for (int c = 1; c < Sn / 4; ++c) {
    asm volatile("s_waitcnt vmcnt(2)" ::: "memory");   // chunk c resident

    const int base = 4 * c;
    const int slot = (c & 3) * 256;
    const int4   tg4 = *(const int4*)&s_tags[base];
    const float4 mk4 = *(const float4*)&s_mask[base];
    const float4 tv4 = *(const float4*)&s_tv[base];
    const float em0r = s_em[slot + jc];
    const float em1r = s_em[slot + 48 + jc];
    const float em2r = s_em[slot + 96 + jc];
    const float em3r = s_em[slot + 144 + jc];

    const float e60 = __builtin_amdgcn_exp2f(em0r * LOG2E) * C6;
    const float e61 = __builtin_amdgcn_exp2f(em1r * LOG2E) * C6;
    const float e62 = __builtin_amdgcn_exp2f(em2r * LOG2E) * C6;
    const float e63 = __builtin_amdgcn_exp2f(em3r * LOG2E) * C6;

    do_step(em0r, e60, mk4.x, tg4.x, tv4.x);
    repack();
    do_step(em1r, e61, mk4.y, tg4.y, tv4.y);
    w *= pendS; M += pendM;
    measure(scA, mA);
    repack();
    do_step(em2r, e62, mk4.z, tg4.z, tv4.z);
    repack();
    do_step(em3r, e63, mk4.w, tg4.w, tv4.w);
    w *= scA; M += mA;
    measure(pendS, pendM);
    repack();

    const int cc = (c + 3 < Sn / 4) ? (c + 3) : (Sn / 4 - 1);
    stage_em(emb, s_em, cc, (c + 3) & 3, j);
  }

  // ---- den = (M + (mtg + 6)*cnt + log2(sum_j w_j * 2^(end'_j))) * ln2 ----
  float z = (j < Tn) ? w * __builtin_amdgcn_exp2f(endt[jc] * LOG2E) : 0.0f;
  #pragma unroll
  for (int off = 32; off; off >>= 1) z += __shfl_xor(z, off);
  const float den = (M + (mtg + 6.0f) * cnt + __builtin_amdgcn_logf(z)) * LN2f;

  const float nm = numer + endt[lt];
  if (j == 0) per_batch[b] = den - nm;
}

__global__ __launch_bounds__(512) void reduce512(const float* __restrict__ pb,
                                                 float* __restrict__ out) {
  __shared__ float red[8];
  const int t = threadIdx.x;
  float v = pb[t];
  #pragma unroll
  for (int off = 32; off; off >>= 1) v += __shfl_xor(v, off);
  if ((t & 63) == 0) red[t >> 6] = v;
  __syncthreads();
  if (t == 0) {
    float s = 0.f;
    #pragma unroll
    for (int wv = 0; wv < 8; ++wv) s += red[wv];
    out[0] = s * (1.0f / 512.0f);
  }
}

extern "C" void kernel_launch(void* const* d_in, const int* in_sizes, int n_in,
                              void* d_out, int out_size, void* d_ws, size_t ws_size,
                              hipStream_t stream) {
  const float* emissions = (const float*)d_in[0];
  const int*   tags      = (const int*)d_in[1];
  const float* mask      = (const float*)d_in[2];
  const float* trans     = (const float*)d_in[3];
  const float* startt    = (const float*)d_in[4];
  const float* endt      = (const float*)d_in[5];
  float* pb = (float*)d_ws;   // 512 floats of scratch

  crf_fwd<<<Bn, 64, 0, stream>>>(emissions, tags, mask, trans, startt, endt, pb);
  reduce512<<<1, 512, 0, stream>>>(pb, (float*)d_out);
}